// Round 11
// baseline (3410.387 us; speedup 1.0000x reference)
//
#include <hip/hip_runtime.h>
#include <stdint.h>

typedef unsigned long long u64;
typedef unsigned int u32;
typedef unsigned short u16;

#define HEADS 16
#define SEQ   4096
#define DH    128
#define TOPK  64
#define NT    512
#define QB    32         // q-rows per block
#define KT    1024       // k-rows per LDS tile
#define DP    16         // d-columns per stage round
#define QBT   8          // q-rows per thread
#define KRT   8          // k-rows per thread (consecutive)
#define CAP   224
#define ZINIT 1.8f

// Map float to order-preserving u32 (IEEE total order for finite values).
__device__ __forceinline__ u32 sortable32(float x) {
  u32 b = __float_as_uint(x);
  return (b & 0x80000000u) ? ~b : (b | 0x80000000u);
}
__device__ __forceinline__ u64 umax64(u64 a, u64 b) { return a > b ? a : b; }

// LDS position of 16B granule (row, s): bank-conflict-free for both the
// linear staging write and the KRT=8-consecutive-row fragment read.
__device__ __forceinline__ int ldspos(int row, int s) {
  int p = row * 4 + (s ^ ((row >> 3) & 3));
  return p ^ (((row >> 5) & 1) << 2);
}

__global__ __launch_bounds__(NT, 2) void si_topk_kernel(
    const float* __restrict__ qg,
    const float* __restrict__ kg,
    int* __restrict__ outg)
{
  #pragma clang fp contract(off)

  __shared__ float4 tile[KT * (DP / 4)];   // 64 KB
  __shared__ float4 qs4[QB * (DH / 4)];    // 16 KB
  __shared__ u32    candS[QB][CAP];        // 28 KB
  __shared__ u16    candJ[QB][CAP];        // 14 KB
  __shared__ u32    cnt[QB];
  __shared__ u32    done[QB];
  __shared__ float  thrv[QB], zlo[QB], zhi[QB], zc[QB], snrm[QB];
  __shared__ int    s_more;

  const int t = threadIdx.x;
  const unsigned bid = blockIdx.x;
  const int h  = (int)(bid & 15u);         // bid&7 pins head-pairs to XCDs
  const int qc = (int)(bid >> 4);          // 0..127

  const int kid = t & 127;                 // owns k-rows 8*kid .. 8*kid+7
  const int qs  = t >> 7;                  // 0..3 (uniform per wave)

  const float* __restrict__ qp = qg + ((size_t)h << 19) + ((size_t)(qc * QB) << 7);
  const float* __restrict__ kh = kg + ((size_t)h << 19);

  const float RECIP = 1.0f / 11.313708498984761f;   // validated round-7 scale

  // ---- stage q once: 32 rows x 128 = 1024 float4 (coalesced) ----
  #pragma unroll
  for (int i = 0; i < 2; ++i) qs4[i * NT + t] = ((const float4*)qp)[i * NT + t];
  if (t < QB) { done[t] = 0; cnt[t] = 0; }
  __syncthreads();

  if (t < QB) {
    const float* qrow = (const float*)&qs4[t * (DH / 4)];
    float s2 = 0.f;
    for (int d = 0; d < DH; ++d) s2 = __builtin_fmaf(qrow[d], qrow[d], s2);
    const float sig = sqrtf(fmaxf(s2, 1e-30f)) * RECIP;
    snrm[t] = sig;
    zlo[t] = 0.0f; zhi[t] = 8.0f; zc[t] = ZINIT;
    thrv[t] = ZINIT * sig;
  }
  __syncthreads();

  // ---- single-pass collect with deterministic bisection retry ----
  for (int attempt = 0; attempt < 24; ++attempt) {
    if (t < QB && !done[t]) cnt[t] = 0;

    float acc[QBT][KRT];
    float4 pre[8];
    // prologue: prefetch round 0 (kt=0, dp=0)
    #pragma unroll
    for (int i = 0; i < 8; ++i) {
      const int a = i * NT + t, row = a >> 2, s = a & 3;
      pre[i] = *(const float4*)&kh[((size_t)row << 7) + s * 4];
    }

    for (int rt = 0; rt < (SEQ / KT) * (DH / DP); ++rt) {   // 32 rounds
      const int kt = rt >> 3, dp = rt & 7;

      __syncthreads();   // previous round's readers done
      #pragma unroll
      for (int i = 0; i < 8; ++i) {
        const int a = i * NT + t, row = a >> 2, s = a & 3;
        tile[ldspos(row, s)] = pre[i];
      }
      if (rt + 1 < 32) {   // T14: issue next round's loads; in flight during FMA
        const int kt2 = (rt + 1) >> 3, dp2 = (rt + 1) & 7;
        #pragma unroll
        for (int i = 0; i < 8; ++i) {
          const int a = i * NT + t, row = a >> 2, s = a & 3;
          pre[i] = *(const float4*)&kh[((size_t)(kt2 * KT + row) << 7) + dp2 * DP + s * 4];
        }
      }
      __syncthreads();   // tile ready

      if (dp == 0) {
        #pragma unroll
        for (int qr = 0; qr < QBT; ++qr)
          #pragma unroll
          for (int e = 0; e < KRT; ++e) acc[qr][e] = 0.f;
      }

      const int swzc = kid & 3;                 // ((8kid+e)>>3)&3
      const int xr2  = ((kid >> 2) & 1) << 2;   // ((8kid+e)>>5)&1 position bit
      #pragma unroll
      for (int c = 0; c < DP / 4; ++c) {
        float4 kf[KRT];
        const int sc = c ^ swzc;
        #pragma unroll
        for (int e = 0; e < KRT; ++e)
          kf[e] = tile[(((kid * 8 + e) * 4 + sc) ^ xr2)];
        #pragma unroll
        for (int qr = 0; qr < QBT; ++qr) {
          // wave-uniform LDS broadcast (qs, qr, dp, c uniform per wave)
          const float4 qv = qs4[(qs * QBT + qr) * (DH / 4) + dp * (DP / 4) + c];
          // exact validated chain: d ascending, one accumulator per dot
          #pragma unroll
          for (int e = 0; e < KRT; ++e) {
            acc[qr][e] = __builtin_fmaf(kf[e].x, qv.x, acc[qr][e]);
            acc[qr][e] = __builtin_fmaf(kf[e].y, qv.y, acc[qr][e]);
            acc[qr][e] = __builtin_fmaf(kf[e].z, qv.z, acc[qr][e]);
            acc[qr][e] = __builtin_fmaf(kf[e].w, qv.w, acc[qr][e]);
          }
        }
      }

      if (dp == 7) {   // this k-tile's 64 dots per thread are complete
        #pragma unroll
        for (int qr = 0; qr < QBT; ++qr) {
          const int row = qs * QBT + qr;
          const bool act = (done[row] == 0);
          const float thr = thrv[row];
          #pragma unroll
          for (int e = 0; e < KRT; ++e) {
            const float s = acc[qr][e] * RECIP;     // validated scale
            if (act && s >= thr) {
              const u32 p = atomicAdd(&cnt[row], 1u);
              if (p < CAP) {
                candS[row][p] = sortable32(s);
                candJ[row][p] = (u16)(kt * KT + kid * 8 + e);
              }
            }
          }
        }
      }
    }

    __syncthreads();
    if (t == 0) s_more = 0;
    __syncthreads();
    if (t < QB && !done[t]) {
      const u32 c = cnt[t];
      if (c >= TOPK && c <= CAP) {
        done[t] = 1;
      } else {
        if (c < TOPK) zhi[t] = zc[t]; else zlo[t] = zc[t];
        zc[t] = 0.5f * (zlo[t] + zhi[t]);
        thrv[t] = zc[t] * snrm[t];
        s_more = 1;
      }
    }
    __syncthreads();
    if (!s_more) break;
  }

  // ---- selection: per wave 4 rows; 64 argmax passes (validated r2-r10) ----
  const int wid = t >> 6, lane = t & 63;
  #pragma unroll
  for (int rr = 0; rr < 4; ++rr) {
    const int row = wid + 8 * rr;
    const u32 n = min(cnt[row], (u32)CAP);   // n >= 64 by construction
    u64 slot[4];
    #pragma unroll
    for (int i = 0; i < 4; ++i) {
      const int idx = lane + 64 * i;
      u64 key = 0ULL;
      if (idx < (int)n)
        key = ((u64)candS[row][idx] << 32) | (u64)(4095 - (int)candJ[row][idx]);
      slot[i] = key;
    }
    const size_t obase = (((size_t)h << 12) | (size_t)(qc * QB + row)) << 6;
    for (int r = 0; r < TOPK; ++r) {
      const u64 lm = umax64(umax64(slot[0], slot[1]), umax64(slot[2], slot[3]));
      u64 v = lm;
      #pragma unroll
      for (int m = 1; m < 64; m <<= 1) {
        unsigned lo = (unsigned)(v & 0xffffffffULL);
        unsigned hi = (unsigned)(v >> 32);
        lo = (unsigned)__shfl_xor((int)lo, m, 64);
        hi = (unsigned)__shfl_xor((int)hi, m, 64);
        v = umax64(v, ((u64)hi << 32) | (u64)lo);
      }
      if (lm == v && v != 0ULL) {     // unique winner: keys globally distinct
        outg[obase + r] = 4095 - (int)(v & 0xFFFULL);
        #pragma unroll
        for (int i = 0; i < 4; ++i) if (slot[i] == v) slot[i] = 0ULL;
      }
    }
  }
}

extern "C" void kernel_launch(void* const* d_in, const int* in_sizes, int n_in,
                              void* d_out, int out_size, void* d_ws, size_t ws_size,
                              hipStream_t stream) {
  const float* q = (const float*)d_in[0];
  const float* k = (const float*)d_in[1];
  int* out = (int*)d_out;
  si_topk_kernel<<<dim3(HEADS * (SEQ / QB)), NT, 0, stream>>>(q, k, out);
}

// Round 12
// 1908.792 us; speedup vs baseline: 1.7867x; 1.7867x over previous
//
#include <hip/hip_runtime.h>
#include <stdint.h>
#include <float.h>

typedef unsigned long long u64;
typedef unsigned int u32;
typedef unsigned short u16;
typedef __attribute__((ext_vector_type(8))) short short8;   // 8 bf16 (4 VGPR)
typedef __attribute__((ext_vector_type(4))) float f32x4;    // MFMA C/D

#define HEADS 16
#define SEQ   4096
#define DH    128
#define TOPK  64
#define NT    512
#define QB    32
#define KT    128        // k-rows per bf16 LDS tile
#define NTILE (SEQ / KT)
#define CAP   224
#define ZINIT 1.8f
#define SLACKC 0.06f     // >= worst-case bf16 filter error (0.055*sigma)

__device__ __forceinline__ u32 sortable32(float x) {
  u32 b = __float_as_uint(x);
  return (b & 0x80000000u) ? ~b : (b | 0x80000000u);
}
__device__ __forceinline__ u64 umax64(u64 a, u64 b) { return a > b ? a : b; }
// fp32 -> bf16 round-to-nearest-even (finite inputs)
__device__ __forceinline__ u16 f2bf(float f) {
  u32 h = __float_as_uint(f);
  return (u16)((h + 0x7FFFu + ((h >> 16) & 1u)) >> 16);
}

__global__ __launch_bounds__(NT, 4) void si_topk_kernel(
    const float* __restrict__ qg,
    const float* __restrict__ kg,
    int* __restrict__ outg)
{
  #pragma clang fp contract(off)

  __shared__ uint4 kbf[KT * 16];          // 32 KB bf16 K-tile, swizzled granules
  __shared__ u32   candS[QB][CAP];        // 28 KB (exact sortable scores)
  __shared__ u16   candJ[QB][CAP];        // 14 KB
  __shared__ u32   cnt[QB], cntex[QB], done[QB];
  __shared__ float thrv[QB], zlo[QB], zhi[QB], zc[QB], snrm[QB];
  __shared__ int   s_more;

  const int t = threadIdx.x;
  const int h  = (int)(blockIdx.x & 15u);   // bid&7 = h&7: heads {x,x+8} -> XCD x
  const int qc = (int)(blockIdx.x >> 4);

  const int w   = t >> 6;          // wave 0..7
  const int l   = t & 63;
  const int qgw = w >> 2;          // q-group: rows qgw*16 .. +15
  const int jgw = w & 3;           // j-group: 32 cols within K-tile

  const float* __restrict__ qp = qg + ((size_t)h << 19) + ((size_t)(qc * QB) << 7);
  const float* __restrict__ kh = kg + ((size_t)h << 19);

  const float RECIP = 1.0f / 11.313708498984761f;   // validated r7 scale

  // ---- per-row stats / state ----
  if (t < QB) {
    const float* qrow = qp + t * DH;
    float s2 = 0.f;
    for (int d = 0; d < DH; ++d) s2 = __builtin_fmaf(qrow[d], qrow[d], s2);
    const float sn = sqrtf(fmaxf(s2, 1e-30f)) * RECIP;  // sd of this row's scores
    snrm[t] = sn;
    zlo[t] = 0.f; zhi[t] = 8.f; zc[t] = ZINIT;
    thrv[t] = ZINIT * sn;
    done[t] = 0; cnt[t] = 0; cntex[t] = 0;
  }
  __syncthreads();

  // ---- A-fragments: wave's 16 q-rows in registers, bf16 ----
  // lane l: m = l&15 (q-row), k-slice d = ds*32 + (l>>4)*8 .. +7
  short8 afrag[4];
  {
    const float* qr = qp + (qgw * 16 + (l & 15)) * DH;
    #pragma unroll
    for (int ds = 0; ds < 4; ++ds) {
      const int d0 = ds * 32 + (l >> 4) * 8;
      const float4 f0 = *(const float4*)(qr + d0);
      const float4 f1 = *(const float4*)(qr + d0 + 4);
      short8 a;
      a[0] = (short)f2bf(f0.x); a[1] = (short)f2bf(f0.y);
      a[2] = (short)f2bf(f0.z); a[3] = (short)f2bf(f0.w);
      a[4] = (short)f2bf(f1.x); a[5] = (short)f2bf(f1.y);
      a[6] = (short)f2bf(f1.z); a[7] = (short)f2bf(f1.w);
      afrag[ds] = a;
    }
  }

  for (int attempt = 0; attempt < 24; ++attempt) {
    // per-lane collect gates for the 4 q-rows this lane's D covers
    float gate[4];
    #pragma unroll
    for (int r = 0; r < 4; ++r) {
      const int row = qgw * 16 + (l >> 4) * 4 + r;
      gate[r] = done[row] ? FLT_MAX : (thrv[row] - SLACKC * snrm[row]);
    }

    // ---- MFMA sweep over 32 K-tiles ----
    for (int kt = 0; kt < NTILE; ++kt) {
      __syncthreads();   // previous tile's readers done
      // stage KT x 128 fp32 -> bf16 (RNE), swizzled 16B granules
      #pragma unroll
      for (int it = 0; it < 4; ++it) {
        const int a = it * NT + t;           // granule id 0..2047
        const int row = a >> 4, g = a & 15;  // 16 granules (8 bf16 each) per row
        const float* src = kh + ((size_t)(kt * KT + row) << 7) + g * 8;
        const float4 f0 = *(const float4*)(src);
        const float4 f1 = *(const float4*)(src + 4);
        short8 sv;
        sv[0] = (short)f2bf(f0.x); sv[1] = (short)f2bf(f0.y);
        sv[2] = (short)f2bf(f0.z); sv[3] = (short)f2bf(f0.w);
        sv[4] = (short)f2bf(f1.x); sv[5] = (short)f2bf(f1.y);
        sv[6] = (short)f2bf(f1.z); sv[7] = (short)f2bf(f1.w);
        kbf[row * 16 + (g ^ (row & 7))] = __builtin_bit_cast(uint4, sv);
      }
      __syncthreads();   // tile ready

      // 2 j-subtiles of 16 cols; accumulate 4 MFMAs over d (K-loop recipe)
      #pragma unroll
      for (int js = 0; js < 2; ++js) {
        const int jloc = jgw * 32 + js * 16 + (l & 15);
        f32x4 c = {0.f, 0.f, 0.f, 0.f};
        #pragma unroll
        for (int ds = 0; ds < 4; ++ds) {
          const int g = ds * 4 + (l >> 4);
          const short8 b = __builtin_bit_cast(short8, kbf[jloc * 16 + (g ^ (jloc & 7))]);
          c = __builtin_amdgcn_mfma_f32_16x16x32_bf16(afrag[ds], b, c, 0, 0, 0);
        }
        const int j = kt * KT + jloc;
        // D layout (m89-verified): col = l&15 (j), row = (l>>4)*4 + reg (q)
        #pragma unroll
        for (int r = 0; r < 4; ++r) {
          const float st = c[r] * RECIP;
          if (st >= gate[r]) {
            const int row = qgw * 16 + (l >> 4) * 4 + r;
            const u32 p = atomicAdd(&cnt[row], 1u);
            if (p < CAP) candJ[row][p] = (u16)j;
          }
        }
      }
    }
    __syncthreads();

    // ---- exact fp32 rescore (bit-identical r7 chain, from global K/Q) ----
    #pragma unroll
    for (int k2 = 0; k2 < 4; ++k2) {
      const int row = w * 4 + k2;
      if (!done[row]) {
        const u32 n = min(cnt[row], (u32)CAP);
        const float thr = thrv[row];
        const float4* qr4 = (const float4*)(qp + row * DH);
        const int nit = ((int)n + 63) >> 6;
        for (int it = 0; it < nit; ++it) {
          const int i = it * 64 + l;
          float s = -FLT_MAX;
          if (i < (int)n) {
            const float4* kr4 = (const float4*)(kh + ((size_t)candJ[row][i] << 7));
            float a0 = 0.f;
            #pragma unroll
            for (int cc = 0; cc < 32; ++cc) {   // d ascending, one chain
              const float4 kv = kr4[cc];
              const float4 qv = qr4[cc];
              a0 = __builtin_fmaf(kv.x, qv.x, a0);
              a0 = __builtin_fmaf(kv.y, qv.y, a0);
              a0 = __builtin_fmaf(kv.z, qv.z, a0);
              a0 = __builtin_fmaf(kv.w, qv.w, a0);
            }
            s = a0 * RECIP;
            candS[row][i] = sortable32(s);
          }
          const u64 m = __ballot(s >= thr);
          if (l == 0) atomicAdd(&cntex[row], (u32)__popcll(m));
        }
      }
    }
    __syncthreads();

    // ---- verify: top-64 guaranteed in candidates iff cntex>=64 & no overflow ----
    if (t == 0) s_more = 0;
    __syncthreads();
    if (t < QB && !done[t]) {
      const u32 c = cnt[t], ce = cntex[t];
      if (c <= CAP && ce >= TOPK) {
        done[t] = 1;
      } else {
        if (c > CAP) zlo[t] = zc[t];   // too many collected -> raise threshold
        else         zhi[t] = zc[t];   // too few exact      -> lower threshold
        zc[t] = 0.5f * (zlo[t] + zhi[t]);
        thrv[t] = zc[t] * snrm[t];
        cnt[t] = 0; cntex[t] = 0;
        s_more = 1;
      }
    }
    __syncthreads();
    if (!s_more) break;
  }

  // ---- selection: wave w rows w*4..w*4+3; validated argmax (r2-r10) ----
  #pragma unroll
  for (int k2 = 0; k2 < 4; ++k2) {
    const int row = w * 4 + k2;
    const u32 n = min(cnt[row], (u32)CAP);
    u64 slot[4];
    #pragma unroll
    for (int i = 0; i < 4; ++i) {
      const int idx = l + 64 * i;
      u64 key = 0ULL;
      if (idx < (int)n)
        key = ((u64)candS[row][idx] << 32) | (u64)(4095 - (int)candJ[row][idx]);
      slot[i] = key;
    }
    const size_t obase = (((size_t)h << 12) | (size_t)(qc * QB + row)) << 6;
    for (int r = 0; r < TOPK; ++r) {
      const u64 lm = umax64(umax64(slot[0], slot[1]), umax64(slot[2], slot[3]));
      u64 v = lm;
      #pragma unroll
      for (int m = 1; m < 64; m <<= 1) {
        unsigned lo = (unsigned)(v & 0xffffffffULL);
        unsigned hi = (unsigned)(v >> 32);
        lo = (unsigned)__shfl_xor((int)lo, m, 64);
        hi = (unsigned)__shfl_xor((int)hi, m, 64);
        v = umax64(v, ((u64)hi << 32) | (u64)lo);
      }
      if (lm == v && v != 0ULL) {   // unique winner: keys globally distinct
        outg[obase + r] = 4095 - (int)(v & 0xFFFULL);
        #pragma unroll
        for (int i = 0; i < 4; ++i) if (slot[i] == v) slot[i] = 0ULL;
      }
    }
  }
}

extern "C" void kernel_launch(void* const* d_in, const int* in_sizes, int n_in,
                              void* d_out, int out_size, void* d_ws, size_t ws_size,
                              hipStream_t stream) {
  const float* q = (const float*)d_in[0];
  const float* k = (const float*)d_in[1];
  int* out = (int*)d_out;
  si_topk_kernel<<<dim3(HEADS * (SEQ / QB)), NT, 0, stream>>>(q, k, out);
}

// Round 13
// 1132.965 us; speedup vs baseline: 3.0101x; 1.6848x over previous
//
#include <hip/hip_runtime.h>
#include <stdint.h>
#include <float.h>

typedef unsigned long long u64;
typedef unsigned int u32;
typedef unsigned short u16;
typedef __attribute__((ext_vector_type(8))) short short8;   // 8 bf16 (4 VGPR)
typedef __attribute__((ext_vector_type(4))) float f32x4;    // MFMA C/D

#define HEADS 16
#define SEQ   4096
#define DH    128
#define TOPK  64
#define NT    512
#define QB    32
#define KT    128        // k-rows per bf16 LDS tile
#define NTILE (SEQ / KT)
#define CAP   192
#define ZINIT 2.0f
#define SLACKC 0.08f     // filter slack in sigma units (>= bf16 worst error)

__device__ __forceinline__ u32 sortable32(float x) {
  u32 b = __float_as_uint(x);
  return (b & 0x80000000u) ? ~b : (b | 0x80000000u);
}
// fp32 -> bf16 round-to-nearest-even (finite inputs)
__device__ __forceinline__ u16 f2bf(float f) {
  u32 h = __float_as_uint(f);
  return (u16)((h + 0x7FFFu + ((h >> 16) & 1u)) >> 16);
}

// wave64 u32 max all-reduce on the VALU via DPP (LLVM gfx9 sequence); no LDS pipe.
__device__ __forceinline__ u32 wave_umax(u32 v) {
  u32 t;
  t = (u32)__builtin_amdgcn_update_dpp((int)v, (int)v, 0xB1,  0xF, 0xF, true);  v = v > t ? v : t; // quad_perm(1,0,3,2)
  t = (u32)__builtin_amdgcn_update_dpp((int)v, (int)v, 0x4E,  0xF, 0xF, true);  v = v > t ? v : t; // quad_perm(2,3,0,1)
  t = (u32)__builtin_amdgcn_update_dpp((int)v, (int)v, 0x141, 0xF, 0xF, true);  v = v > t ? v : t; // row_half_mirror
  t = (u32)__builtin_amdgcn_update_dpp((int)v, (int)v, 0x140, 0xF, 0xF, true);  v = v > t ? v : t; // row_mirror
  t = (u32)__builtin_amdgcn_update_dpp((int)v, (int)v, 0x142, 0xA, 0xF, false); v = v > t ? v : t; // bcast15 -> rows 1,3
  t = (u32)__builtin_amdgcn_update_dpp((int)v, (int)v, 0x143, 0xC, 0xF, false); v = v > t ? v : t; // bcast31 -> rows 2,3
  return (u32)__builtin_amdgcn_readlane((int)v, 63);
}
__device__ __forceinline__ u32 wave_umin(u32 v) {
  u32 t;
  t = (u32)__builtin_amdgcn_update_dpp((int)v, (int)v, 0xB1,  0xF, 0xF, true);  v = v < t ? v : t;
  t = (u32)__builtin_amdgcn_update_dpp((int)v, (int)v, 0x4E,  0xF, 0xF, true);  v = v < t ? v : t;
  t = (u32)__builtin_amdgcn_update_dpp((int)v, (int)v, 0x141, 0xF, 0xF, true);  v = v < t ? v : t;
  t = (u32)__builtin_amdgcn_update_dpp((int)v, (int)v, 0x140, 0xF, 0xF, true);  v = v < t ? v : t;
  t = (u32)__builtin_amdgcn_update_dpp((int)v, (int)v, 0x142, 0xA, 0xF, false); v = v < t ? v : t;
  t = (u32)__builtin_amdgcn_update_dpp((int)v, (int)v, 0x143, 0xC, 0xF, false); v = v < t ? v : t;
  return (u32)__builtin_amdgcn_readlane((int)v, 63);
}

__global__ __launch_bounds__(NT, 4) void si_topk_kernel(
    const float* __restrict__ qg,
    const float* __restrict__ kg,
    int* __restrict__ outg)
{
  #pragma clang fp contract(off)

  __shared__ uint4 kbf[KT * 16];          // 32 KB: bf16 filter tile / rescore 8x4KB
  __shared__ u32   candS[QB][CAP];        // 24 KB exact sortable scores
  __shared__ u16   candJ[QB][CAP];        // 12 KB
  __shared__ u32   cnt[QB], cntex[QB], done[QB];
  __shared__ float thrv[QB], zlo[QB], zhi[QB], zc[QB], snrm[QB];
  __shared__ int   s_more;

  const int t = threadIdx.x;
  const int h  = (int)(blockIdx.x & 15u);   // bid&7 = h&7: heads {x,x+8} -> XCD x
  const int qc = (int)(blockIdx.x >> 4);

  const int w   = t >> 6;          // wave 0..7
  const int l   = t & 63;
  const int qgw = w >> 2;          // q-group: rows qgw*16 .. +15
  const int jgw = w & 3;           // j-group: 32 cols within K-tile

  const float* __restrict__ qp = qg + ((size_t)h << 19) + ((size_t)(qc * QB) << 7);
  const float* __restrict__ kh = kg + ((size_t)h << 19);

  const float RECIP = 1.0f / 11.313708498984761f;   // validated r7 scale

  // ---- per-row stats / state ----
  if (t < QB) {
    const float* qrow = qp + t * DH;
    float s2 = 0.f;
    for (int d = 0; d < DH; ++d) s2 = __builtin_fmaf(qrow[d], qrow[d], s2);
    const float sn = sqrtf(fmaxf(s2, 1e-30f)) * RECIP;  // sd of this row's scores
    snrm[t] = sn;
    zlo[t] = 0.f; zhi[t] = 8.f; zc[t] = ZINIT;
    thrv[t] = ZINIT * sn;
    done[t] = 0; cnt[t] = 0; cntex[t] = 0;
  }
  __syncthreads();

  // ---- A-fragments: wave's 16 q-rows in registers, bf16 (r12-validated) ----
  short8 afrag[4];
  {
    const float* qr = qp + (qgw * 16 + (l & 15)) * DH;
    #pragma unroll
    for (int ds = 0; ds < 4; ++ds) {
      const int d0 = ds * 32 + (l >> 4) * 8;
      const float4 f0 = *(const float4*)(qr + d0);
      const float4 f1 = *(const float4*)(qr + d0 + 4);
      short8 a;
      a[0] = (short)f2bf(f0.x); a[1] = (short)f2bf(f0.y);
      a[2] = (short)f2bf(f0.z); a[3] = (short)f2bf(f0.w);
      a[4] = (short)f2bf(f1.x); a[5] = (short)f2bf(f1.y);
      a[6] = (short)f2bf(f1.z); a[7] = (short)f2bf(f1.w);
      afrag[ds] = a;
    }
  }

  for (int attempt = 0; attempt < 24; ++attempt) {
    if (t < QB && !done[t]) cnt[t] = 0;

    float gate[4];
    #pragma unroll
    for (int r = 0; r < 4; ++r) {
      const int row = qgw * 16 + (l >> 4) * 4 + r;
      gate[r] = done[row] ? FLT_MAX : (thrv[row] - SLACKC * snrm[row]);
    }

    // ---- filter: MFMA sweep with T14 register prefetch ----
    float4 pre[4][2];
    #pragma unroll
    for (int it = 0; it < 4; ++it) {
      const int a = it * NT + t;
      const int row = a >> 4, g = a & 15;
      const float* src = kh + ((size_t)row << 7) + g * 8;
      pre[it][0] = *(const float4*)(src);
      pre[it][1] = *(const float4*)(src + 4);
    }

    for (int kt = 0; kt < NTILE; ++kt) {
      __syncthreads();   // previous tile's readers done
      #pragma unroll
      for (int it = 0; it < 4; ++it) {
        const int a = it * NT + t;
        const int row = a >> 4, g = a & 15;
        short8 sv;
        sv[0] = (short)f2bf(pre[it][0].x); sv[1] = (short)f2bf(pre[it][0].y);
        sv[2] = (short)f2bf(pre[it][0].z); sv[3] = (short)f2bf(pre[it][0].w);
        sv[4] = (short)f2bf(pre[it][1].x); sv[5] = (short)f2bf(pre[it][1].y);
        sv[6] = (short)f2bf(pre[it][1].z); sv[7] = (short)f2bf(pre[it][1].w);
        kbf[row * 16 + (g ^ (row & 7))] = __builtin_bit_cast(uint4, sv);
      }
      if (kt + 1 < NTILE) {   // issue next tile's loads; in flight across MFMA
        #pragma unroll
        for (int it = 0; it < 4; ++it) {
          const int a = it * NT + t;
          const int row = a >> 4, g = a & 15;
          const float* src = kh + ((size_t)((kt + 1) * KT + row) << 7) + g * 8;
          pre[it][0] = *(const float4*)(src);
          pre[it][1] = *(const float4*)(src + 4);
        }
      }
      __syncthreads();   // tile ready

      #pragma unroll
      for (int js = 0; js < 2; ++js) {
        const int jloc = jgw * 32 + js * 16 + (l & 15);
        f32x4 c = {0.f, 0.f, 0.f, 0.f};
        #pragma unroll
        for (int ds = 0; ds < 4; ++ds) {
          const int g = ds * 4 + (l >> 4);
          const short8 b = __builtin_bit_cast(short8, kbf[jloc * 16 + (g ^ (jloc & 7))]);
          c = __builtin_amdgcn_mfma_f32_16x16x32_bf16(afrag[ds], b, c, 0, 0, 0);
        }
        const int j = kt * KT + jloc;
        // D layout (m89-verified): col = l&15 (j), row = (l>>4)*4 + reg (q)
        #pragma unroll
        for (int r = 0; r < 4; ++r) {
          const float st = c[r] * RECIP;
          if (st >= gate[r]) {
            const int row = qgw * 16 + (l >> 4) * 4 + r;
            const u32 p = atomicAdd(&cnt[row], 1u);
            if (p < CAP) candJ[row][p] = (u16)j;
          }
        }
      }
    }
    __syncthreads();   // filter done; kbf free for rescore reuse

    // ---- exact fp32 rescore: wave-private phased LDS staging (4KB/wave) ----
    {
      float4* stg = ((float4*)kbf) + w * 256;   // 64 rows x 4 granules
      for (int k2 = 0; k2 < 4; ++k2) {
        const int row = w * 4 + k2;
        if (done[row]) continue;                 // wave-uniform
        const u32 n = min(cnt[row], (u32)CAP);
        const float thr = thrv[row];
        const float* qrow = qp + row * DH;       // wave-uniform -> scalar loads
        const int nb = ((int)n + 63) >> 6;
        for (int b = 0; b < nb; ++b) {
          const int base = b * 64;
          const int cidx = base + l;
          const bool cv = cidx < (int)n;
          float a0 = 0.f;
          for (int p = 0; p < 8; ++p) {
            float4 tv[4];
            #pragma unroll
            for (int i = 0; i < 4; ++i) {        // 4-lane groups load full 64B lines
              const int sidx = base + 16 * i + (l >> 2);
              const int jr = (sidx < (int)n) ? (int)candJ[row][sidx] : 0;
              tv[i] = *(const float4*)&kh[((size_t)jr << 7) + (size_t)(4 * p + (l & 3)) * 4];
            }
            #pragma unroll
            for (int i = 0; i < 4; ++i) {
              const int r2 = 16 * i + (l >> 2);
              stg[r2 * 4 + (((l & 3) + r2) & 3)] = tv[i];   // rotation swizzle
            }
            asm volatile("s_waitcnt lgkmcnt(0)" ::: "memory");
            __builtin_amdgcn_sched_barrier(0);   // rule #18
            #pragma unroll
            for (int g = 0; g < 4; ++g) {        // d ascending: 16p + 4g + {0..3}
              const float4 kv = stg[l * 4 + ((g + l) & 3)];
              const float4 qv = *(const float4*)(qrow + 16 * p + 4 * g);
              a0 = __builtin_fmaf(kv.x, qv.x, a0);
              a0 = __builtin_fmaf(kv.y, qv.y, a0);
              a0 = __builtin_fmaf(kv.z, qv.z, a0);
              a0 = __builtin_fmaf(kv.w, qv.w, a0);
            }
          }
          const float s = a0 * RECIP;            // exact validated chain + scale
          if (cv) candS[row][cidx] = sortable32(s);
          const u64 mm = __ballot(cv && (s >= thr));
          if (l == 0) atomicAdd(&cntex[row], (u32)__popcll(mm));
        }
      }
    }

    // ---- verify: top-64 guaranteed collected iff cnt<=CAP && cntex>=64 ----
    __syncthreads();
    if (t == 0) s_more = 0;
    __syncthreads();
    if (t < QB && !done[t]) {
      const u32 c = cnt[t], ce = cntex[t];
      if (c <= CAP && ce >= TOPK) {
        done[t] = 1;
      } else {
        if (c > CAP) zlo[t] = zc[t];   // too many collected -> raise threshold
        else         zhi[t] = zc[t];   // too few exact      -> lower threshold
        zc[t] = 0.5f * (zlo[t] + zhi[t]);
        thrv[t] = zc[t] * snrm[t];
        cntex[t] = 0;
        s_more = 1;
      }
    }
    __syncthreads();
    if (!s_more) break;
  }

  // ---- selection: DPP rank extraction (VALU pipe; ties -> lowest j first) ----
  for (int k2 = 0; k2 < 4; ++k2) {
    const int row = w * 4 + k2;
    const u32 n = min(cnt[row], (u32)CAP);
    u32 sc[3], jx[3];
    #pragma unroll
    for (int i = 0; i < 3; ++i) {
      const int idx = l + 64 * i;
      const bool v2 = idx < (int)n;
      sc[i] = v2 ? candS[row][idx] : 0u;         // 0 < sortable32(any finite)
      jx[i] = v2 ? (u32)candJ[row][idx] : 0xFFFFu;
    }
    const size_t obase = (((size_t)h << 12) | (size_t)(qc * QB + row)) << 6;
    for (int r = 0; r < TOPK; ++r) {
      u32 lm = sc[0] > sc[1] ? sc[0] : sc[1];
      lm = lm > sc[2] ? lm : sc[2];
      const u32 M = wave_umax(lm);
      u32 myj = 0xFFFFFFFFu; int slot = -1;
      if (sc[2] == M) { myj = jx[2]; slot = 2; }
      if (sc[1] == M && jx[1] < myj) { myj = jx[1]; slot = 1; }
      if (sc[0] == M && jx[0] < myj) { myj = jx[0]; slot = 0; }
      const u32 J = wave_umin(myj);              // tie-break: lowest index
      if (slot >= 0 && myj == J) {
        outg[obase + r] = (int)J;
        sc[slot] = 0u;                            // consume exactly one
      }
    }
  }
}

extern "C" void kernel_launch(void* const* d_in, const int* in_sizes, int n_in,
                              void* d_out, int out_size, void* d_ws, size_t ws_size,
                              hipStream_t stream) {
  const float* q = (const float*)d_in[0];
  const float* k = (const float*)d_in[1];
  int* out = (int*)d_out;
  si_topk_kernel<<<dim3(HEADS * (SEQ / QB)), NT, 0, stream>>>(q, k, out);
}